// Round 7
// baseline (1935.129 us; speedup 1.0000x reference)
//
#include <hip/hip_runtime.h>

// GRU B=256,T=2000,I=23,H=128 (r,z,n order) + mean over T.
// 1 batch row per block, 256 blocks (1/CU), 1024 threads = 16 waves (4/SIMD).
// Slot sl = wave*4 + (l>>4); slot owns j in {2sl,2sl+1}. Lane kt=l&15 covers
// k=kt*8..+8. 8 accumulators/thread = {r,z,ghn,gxn}x{j0,j1}, acc[i] <-> q=i^p,
// p=bitrev3(l&7); 4-level XOR fold + quad_perm gathers (verified r3/r5/r6),
// in-lane epilogue, ONE barrier per step.
//
// R7 CHANGE: f16 dot2 for the recurrent dot.
//  - W_hh packed half2 in 32 VGPRs (was 64 f32 -> acc-reg pressure gone)
//  - h stored in LDS as f16: row kt = 8 halves = 16 B -> ONE ds_read_b128
//    per thread (was two); DS h-traffic halves
//  - inner loop: 32 x v_dot2_f32_f16 (2 MAC/instr, f32 accumulate; was 64 FMA)
//  - h_reg state stays f32 (only the LDS copy feeding dots is f16-quantized,
//    so quantization error does not accumulate in the recurrence state)

#define Bb 256
#define Tt 2000
#define Ii 23
#define Hh 128

typedef _Float16 half2_t __attribute__((ext_vector_type(2)));

template <int ctrl>
__device__ __forceinline__ float dpp_movf(float v) {
    int r = __builtin_amdgcn_update_dpp(0, __builtin_bit_cast(int, v),
                                        ctrl, 0xf, 0xf, true);
    return __builtin_bit_cast(float, r);
}

__global__ __launch_bounds__(1024, 4)
void gru_fused(const float* __restrict__ x,     // [B,T,I]
               const float* __restrict__ W_ih,  // [3H,I]
               const float* __restrict__ W_hh,  // [3H,H]
               const float* __restrict__ b_ih,  // [3H]
               const float* __restrict__ b_hh,  // [3H]
               float* __restrict__ out)         // [B,H]
{
    const int b   = blockIdx.x;
    const int t   = threadIdx.x;
    const int wid = t >> 6;
    const int l   = t & 63;
    const int kt  = l & 15;                 // k in [kt*8, kt*8+8)
    const int gl  = l >> 4;
    const int sl  = wid * 4 + gl;           // 0..63
    const int p   = ((l & 1) << 2) | (l & 2) | ((l >> 2) & 1); // bitrev3

    __shared__ __align__(16) _Float16 hbuf[16 * 8]; // h[j] at [j], row kt = 16 B
    __shared__ float xbuf[4][24];                   // 4-step x ring, [23]=0 pad

    // ---- weights: acc i <-> quantity q = i^p; q = c*2+e; j = 2*sl+e ----
    const int xi0 = (kt < 7) ? kt * 2 : kt + 7;   // kt<7 owns 2 x-elems, else 1
    const bool two_x = (kt < 7);
    half2_t w2[8][4];                  // packed W_hh pairs: 32 VGPRs
    float wx0[8], wx1[8];
    #pragma unroll
    for (int i = 0; i < 8; ++i) {
        const int q = i ^ p;
        const int e = q & 1, c = q >> 1;
        const int jq = 2 * sl + e;
        const int row = (c == 0) ? jq : (c == 1) ? (Hh + jq) : (2 * Hh + jq);
        #pragma unroll
        for (int cc = 0; cc < 4; ++cc) {
            float wa = (c == 3) ? 0.0f : W_hh[(size_t)row * Hh + kt * 8 + 2 * cc];
            float wb = (c == 3) ? 0.0f : W_hh[(size_t)row * Hh + kt * 8 + 2 * cc + 1];
            half2_t hw; hw.x = (_Float16)wa; hw.y = (_Float16)wb;
            w2[i][cc] = hw;
        }
        // x-side: r,z fold x into same acc; nx gets only x; nh gets none
        wx0[i] = (c == 2) ? 0.0f : W_ih[(size_t)row * Ii + xi0];
        wx1[i] = (c == 2 || !two_x) ? 0.0f : W_ih[(size_t)row * Ii + xi0 + 1];
    }

    // per-lane j (valid on r-lanes; harmless elsewhere)
    const int ej = (l >> 2) & 1;
    const int j  = 2 * sl + ej;
    const float bias_r  = b_ih[j] + b_hh[j];
    const float bias_z  = b_ih[Hh + j] + b_hh[Hh + j];
    const float bias_nh = b_hh[2 * Hh + j];
    const float bias_nx = b_ih[2 * Hh + j];
    const bool writer = ((l & 3) == 0) && ((l & 8) == 0);

    const float* xrow = x + (size_t)b * Tt * Ii;

    // ---- init ----
    if (t < 128) hbuf[t] = (_Float16)0.0f;
    if (t < 23) { xbuf[0][t] = xrow[t]; xbuf[1][t] = xrow[Ii + t]; }
    if (t == 23) { xbuf[0][23] = 0.0f; xbuf[1][23] = 0.0f;
                   xbuf[2][23] = 0.0f; xbuf[3][23] = 0.0f; }
    float x_pend = (t < 23) ? xrow[2 * Ii + t] : 0.0f;   // x[step 2]
    const float* xptr = xrow + 3 * Ii + t;               // next load: step 3
    float h_reg = 0.0f, acc_mean = 0.0f;
    __syncthreads();

    for (int step = 0; step < Tt; ++step) {
        // issue load for step+3 (consumed 3 iterations later)
        float x_next = 0.0f;
        if (t < 23 && step + 3 < Tt) x_next = *xptr;
        xptr += Ii;

        // ---- h tile: 8 f16 via ONE b128 (16 addrs x 4-lane broadcast) ----
        const uint4 raw = *reinterpret_cast<const uint4*>(&hbuf[kt * 8]);
        const half2_t h2[4] = {
            __builtin_bit_cast(half2_t, raw.x), __builtin_bit_cast(half2_t, raw.y),
            __builtin_bit_cast(half2_t, raw.z), __builtin_bit_cast(half2_t, raw.w)};
        const float xa = xbuf[step & 3][xi0];
        const float xb = xbuf[step & 3][xi0 + 1];   // index <= 23 (pad)

        // ---- MACs: f32 x-proj init + 32 x dot2 (64 MACs) ----
        float a0[8];
        #pragma unroll
        for (int i = 0; i < 8; ++i) a0[i] = fmaf(wx0[i], xa, wx1[i] * xb);
        #pragma unroll
        for (int cc = 0; cc < 4; ++cc) {
            #pragma unroll
            for (int i = 0; i < 8; ++i)
                a0[i] = __builtin_amdgcn_fdot2(w2[i][cc], h2[cc], a0[i], false);
        }

        // ---- fold across 16 kt lanes (xor1<->acc^4, xor2<->acc^2,
        //      xor4<->acc^1 (shfl), xor8 duplicate) ----
        float f0 = a0[0] + dpp_movf<0xB1>(a0[4]);
        float f1 = a0[1] + dpp_movf<0xB1>(a0[5]);
        float f2 = a0[2] + dpp_movf<0xB1>(a0[6]);
        float f3 = a0[3] + dpp_movf<0xB1>(a0[7]);
        float c0 = f0 + dpp_movf<0x4E>(f2);
        float c1 = f1 + dpp_movf<0x4E>(f3);
        float d  = c0 + __shfl_xor(c1, 4, 64);
        float v  = d + dpp_movf<0x128>(d);
        // lane l now holds total for quantity q = p(l&7)

        // ---- gather the triple into the r-lanes (pure quad-perm DPP) ----
        float s_r = v + bias_r;                       // own quantity (q = e)
        float s_z = dpp_movf<0x4E>(v) + bias_z;       // q^2 at lane^2
        float ghn = dpp_movf<0xB1>(v) + bias_nh;      // q^4 at lane^1
        float gxn = dpp_movf<0x1B>(v) + bias_nx;      // q^6 at lane^3

        // ---- in-lane epilogue (redundant on non-r lanes, never written) ----
        float r = 1.0f / (1.0f + __expf(-s_r));
        float z = 1.0f / (1.0f + __expf(-s_z));
        float npre = fmaf(r, ghn, gxn);
        float n = 2.0f / (1.0f + __expf(-2.0f * npre)) - 1.0f;
        float h_new = fmaf(z, h_reg - n, n);
        acc_mean += h_new;
        h_reg = h_new;
        if (writer) hbuf[j] = (_Float16)h_new;        // ds_write_b16

        // ---- stage x[step+2] (loaded at iter step-1) ----
        if (t < 23 && step + 2 < Tt) xbuf[(step + 2) & 3][t] = x_pend;
        x_pend = x_next;

        __syncthreads();   // the ONLY barrier per step
    }

    if (writer) out[(size_t)b * Hh + j] = acc_mean * (1.0f / Tt);
}

extern "C" void kernel_launch(void* const* d_in, const int* in_sizes, int n_in,
                              void* d_out, int out_size, void* d_ws, size_t ws_size,
                              hipStream_t stream) {
    const float* x    = (const float*)d_in[0];
    const float* W_ih = (const float*)d_in[1];
    const float* W_hh = (const float*)d_in[2];
    const float* b_ih = (const float*)d_in[3];
    const float* b_hh = (const float*)d_in[4];
    float* out = (float*)d_out;

    gru_fused<<<Bb, 1024, 0, stream>>>(x, W_ih, W_hh, b_ih, b_hh, out);
}

// Round 8
// 1681.758 us; speedup vs baseline: 1.1507x; 1.1507x over previous
//
#include <hip/hip_runtime.h>

// GRU B=256,T=2000,I=23,H=128 (r,z,n order) + mean over T.
// 1 batch row per block, 256 blocks (1/CU), 1024 threads = 16 waves (4/SIMD).
// Slot sl = wave*4 + (l>>4); slot owns j in {2sl,2sl+1}. Lane kt=l&15 covers
// k=kt*8..+8. 8 accumulators/thread = {r,z,ghn,gxn}x{j0,j1}, acc[i] <-> q=i^p,
// p=bitrev3(l&7); 4-level XOR fold + quad_perm gathers (verified r3/r5),
// in-lane epilogue, ONE barrier per step. Body = r5 (best-known numerics).
//
// R8 CHANGE: chunked x staging. __syncthreads drains vmcnt(0) (compiler
// emits s_waitcnt vmcnt(0) before s_barrier), so ANY global load issued in
// an iteration is force-completed at that iteration's barrier -> r1..r7 all
// exposed ~900 cyc of x HBM-miss latency per step (the ~2000-cyc step
// plateau; r6's ring couldn't help, r7's instr cut didn't matter).
// Now x is loaded once per 32-step chunk: threads 0..735 hold the NEXT
// chunk in a register (issued one chunk early), ds_write it at the chunk
// boundary (+1 barrier per chunk). 31 of 32 inner iterations have zero
// outstanding vmem -> barrier drain is free; chunk-iter-0 covers the load.

#define Bb 256
#define Tt 2000
#define Ii 23
#define Hh 128
#define CH 32                      // chunk: timesteps staged per load

template <int ctrl>
__device__ __forceinline__ float dpp_movf(float v) {
    int r = __builtin_amdgcn_update_dpp(0, __builtin_bit_cast(int, v),
                                        ctrl, 0xf, 0xf, true);
    return __builtin_bit_cast(float, r);
}

__global__ __launch_bounds__(1024, 4)
void gru_fused(const float* __restrict__ x,     // [B,T,I]
               const float* __restrict__ W_ih,  // [3H,I]
               const float* __restrict__ W_hh,  // [3H,H]
               const float* __restrict__ b_ih,  // [3H]
               const float* __restrict__ b_hh,  // [3H]
               float* __restrict__ out)         // [B,H]
{
    const int b   = blockIdx.x;
    const int t   = threadIdx.x;
    const int wid = t >> 6;
    const int l   = t & 63;
    const int kt  = l & 15;                 // k in [kt*8, kt*8+8)
    const int gl  = l >> 4;
    const int sl  = wid * 4 + gl;           // 0..63
    const int p   = ((l & 1) << 2) | (l & 2) | ((l >> 2) & 1); // bitrev3

    __shared__ __align__(16) float hbuf[16 * 12];  // h[k=8a+c] at [a*12+c]
    __shared__ float xs[CH * 24];                  // staged x chunk, col 23 = 0 pad

    // ---- weights: acc i <-> quantity q = i^p; q = c*2+e; j = 2*sl+e ----
    const int xi0 = (kt < 7) ? kt * 2 : kt + 7;   // kt<7 owns 2 x-elems, else 1
    const bool two_x = (kt < 7);
    float whh[8][8];
    float wx0[8], wx1[8];
    #pragma unroll
    for (int i = 0; i < 8; ++i) {
        const int q = i ^ p;
        const int e = q & 1, c = q >> 1;
        const int jq = 2 * sl + e;
        const int row = (c == 0) ? jq : (c == 1) ? (Hh + jq) : (2 * Hh + jq);
        #pragma unroll
        for (int k = 0; k < 8; ++k)
            whh[i][k] = (c == 3) ? 0.0f : W_hh[(size_t)row * Hh + kt * 8 + k];
        // x-side: r,z fold x into same acc; nx gets only x; nh gets none
        wx0[i] = (c == 2) ? 0.0f : W_ih[(size_t)row * Ii + xi0];
        wx1[i] = (c == 2 || !two_x) ? 0.0f : W_ih[(size_t)row * Ii + xi0 + 1];
    }

    // per-lane j (valid on r-lanes; harmless elsewhere)
    const int ej = (l >> 2) & 1;
    const int j  = 2 * sl + ej;
    const float bias_r  = b_ih[j] + b_hh[j];
    const float bias_z  = b_ih[Hh + j] + b_hh[Hh + j];
    const float bias_nh = b_hh[2 * Hh + j];
    const float bias_nx = b_ih[2 * Hh + j];
    const bool writer = ((l & 3) == 0) && ((l & 8) == 0);

    const float* xrow = x + (size_t)b * Tt * Ii;

    // staging role: threads 0..735 own one float of each chunk
    const bool stager   = (t < CH * Ii);
    const int  stage_off = (t / Ii) * 24 + (t % Ii);  // one-time magic-div

    // ---- init ----
    if (t < 192) hbuf[t] = 0.0f;
    if (t < CH)  xs[t * 24 + 23] = 0.0f;             // pad column, never rewritten
    // preload chunk 0 into the pending register
    float x_pend = (stager) ? xrow[t] : 0.0f;        // chunk 0 fully in range
    float h_reg = 0.0f, acc_mean = 0.0f;
    __syncthreads();

    for (int c0 = 0; c0 < Tt; c0 += CH) {
        // ---- staging: commit pending chunk to LDS, then issue next load ----
        if (stager) xs[stage_off] = x_pend;
        __syncthreads();
        {
            const int nbase = (c0 + CH) * Ii + t;
            x_pend = (stager && nbase < Tt * Ii) ? xrow[nbase] : 0.0f;
        }

        const int ns = (Tt - c0 < CH) ? (Tt - c0) : CH;
        for (int s = 0; s < ns; ++s) {
            // ---- h tile: 8 f32 via 2x b128 (16 addrs x 4-lane broadcast) ----
            const float4 hA = *reinterpret_cast<const float4*>(&hbuf[kt * 12]);
            const float4 hB = *reinterpret_cast<const float4*>(&hbuf[kt * 12 + 4]);
            const float xa = xs[s * 24 + xi0];
            const float xb = xs[s * 24 + xi0 + 1];   // col 23 = 0 pad

            // ---- MACs: x-proj init + 8x8 recurrent tile ----
            float a0[8];
            #pragma unroll
            for (int i = 0; i < 8; ++i) a0[i] = fmaf(wx0[i], xa, wx1[i] * xb);
            const float hv[8] = {hA.x, hA.y, hA.z, hA.w, hB.x, hB.y, hB.z, hB.w};
            #pragma unroll
            for (int k = 0; k < 8; ++k) {
                #pragma unroll
                for (int i = 0; i < 8; ++i)
                    a0[i] = fmaf(whh[i][k], hv[k], a0[i]);
            }

            // ---- fold across 16 kt lanes (xor1<->acc^4, xor2<->acc^2,
            //      xor4<->acc^1 (shfl), xor8 duplicate) ----
            float f0 = a0[0] + dpp_movf<0xB1>(a0[4]);
            float f1 = a0[1] + dpp_movf<0xB1>(a0[5]);
            float f2 = a0[2] + dpp_movf<0xB1>(a0[6]);
            float f3 = a0[3] + dpp_movf<0xB1>(a0[7]);
            float c0f = f0 + dpp_movf<0x4E>(f2);
            float c1f = f1 + dpp_movf<0x4E>(f3);
            float d  = c0f + __shfl_xor(c1f, 4, 64);
            float v  = d + dpp_movf<0x128>(d);
            // lane l now holds total for quantity q = p(l&7)

            // ---- gather the triple (pure quad-perm DPP) ----
            float s_r = v + bias_r;                       // own quantity (q = e)
            float s_z = dpp_movf<0x4E>(v) + bias_z;       // q^2 at lane^2
            float ghn = dpp_movf<0xB1>(v) + bias_nh;      // q^4 at lane^1
            float gxn = dpp_movf<0x1B>(v) + bias_nx;      // q^6 at lane^3

            // ---- in-lane epilogue ----
            float r = 1.0f / (1.0f + __expf(-s_r));
            float z = 1.0f / (1.0f + __expf(-s_z));
            float npre = fmaf(r, ghn, gxn);
            float n = 2.0f / (1.0f + __expf(-2.0f * npre)) - 1.0f;
            float h_new = fmaf(z, h_reg - n, n);
            acc_mean += h_new;
            h_reg = h_new;
            if (writer) hbuf[(j >> 3) * 12 + (j & 7)] = h_new;

            __syncthreads();   // the ONLY barrier per step (no vmem in flight)
        }
    }

    if (writer) out[(size_t)b * Hh + j] = acc_mean * (1.0f / Tt);
}

extern "C" void kernel_launch(void* const* d_in, const int* in_sizes, int n_in,
                              void* d_out, int out_size, void* d_ws, size_t ws_size,
                              hipStream_t stream) {
    const float* x    = (const float*)d_in[0];
    const float* W_ih = (const float*)d_in[1];
    const float* W_hh = (const float*)d_in[2];
    const float* b_ih = (const float*)d_in[3];
    const float* b_hh = (const float*)d_in[4];
    float* out = (float*)d_out;

    gru_fused<<<Bb, 1024, 0, stream>>>(x, W_ih, W_hh, b_ih, b_hh, out);
}